// Round 4
// baseline (364.549 us; speedup 1.0000x reference)
//
#include <hip/hip_runtime.h>
#include <cstdint>
#include <cstddef>

// ---------------------------------------------------------------------------
// BoxEmbeddingCBM: B=4096, F=2048, K=64, D=8, VOL_TEMP=0.5, INT_TEMP=0.1
//
// ROUND 11:
//   - gemm_theta: XCD-ownership block mapping. Theory: gemm is LLC-BW-bound
//     on 512 MB of redundant tile re-reads (R7/R8/R10 all ~120us despite
//     different inner structures). xcd = bid&7 owns m-tiles {4k..4k+3} x all
//     8 n-tiles -> A-slab 4 MB stays in the XCD's private L2 across n;
//     traffic 512 -> ~110 MB. Inner loop / swizzle unchanged from R10.
//   - fused_pair: circular-offset pair mapping. Thread owns box i=t&63 in
//     registers; computes o=0..31 (+32 for t<64), j=(i+o)&63. Removes
//     sqrt/index math + tail predication, halves pair LDS reads. Math is
//     symmetric in (i,j) -> bit-identical results. sprod[33][66] layout:
//     phase-B lookup <=2-way bank aliasing (free).
// Outputs f32. ws: Bt 8 MB + Th 16 MB + Ah 16 MB + Al 16 MB = 56 MB.
// ---------------------------------------------------------------------------

typedef __bf16 bf16_t;
typedef __bf16 bf16x4 __attribute__((ext_vector_type(4)));
typedef __bf16 bf16x8 __attribute__((ext_vector_type(8)));
typedef float floatx4 __attribute__((ext_vector_type(4)));

#define LOG2E 1.4426950408889634f
#define LN2 0.6931471805599453f
#define K1C 14.426950408889634f  /* LOG2E / INT_TEMP */
#define K3C 2.8853900817779268f  /* 2*LOG2E  (vol beta = 1/VOL_TEMP = 2) */

__device__ __forceinline__ float ex2(float x) { return __builtin_exp2f(x); }
__device__ __forceinline__ float lg2(float x) { return __builtin_log2f(x); }

__device__ __forceinline__ void gload16(const bf16_t* g, bf16_t* l) {
  __builtin_amdgcn_global_load_lds(
      (const __attribute__((address_space(1))) void*)g,
      (__attribute__((address_space(3))) void*)l, 16, 0, 0);
}

// ---------------- P1: split A [4096][2048] f32 -> Ah/Al bf16 ---------------
__global__ __launch_bounds__(256) void prep_a(const float* __restrict__ A,
                                              bf16_t* __restrict__ Ah,
                                              bf16_t* __restrict__ Al) {
  const size_t i = ((size_t)blockIdx.x * 256 + threadIdx.x) * 8;
  const float4 v0 = *reinterpret_cast<const float4*>(A + i);
  const float4 v1 = *reinterpret_cast<const float4*>(A + i + 4);
  const float x[8] = {v0.x, v0.y, v0.z, v0.w, v1.x, v1.y, v1.z, v1.w};
  bf16x8 h, l;
#pragma unroll
  for (int u = 0; u < 8; ++u) {
    const __bf16 hv = (__bf16)x[u];
    h[u] = hv;
    l[u] = (__bf16)(x[u] - (float)hv);
  }
  *reinterpret_cast<bf16x8*>(Ah + i) = h;
  *reinterpret_cast<bf16x8*>(Al + i) = l;
}

// ---------------- P2: transpose+split Wp into Bt [1024][4096] --------------
// row n = kc*16+d; cols 0..2047 = hi(bf16), 2048..4095 = lo(bf16)
__global__ __launch_bounds__(256, 2) void prep_b(const float* __restrict__ Wp,
                                                 bf16_t* __restrict__ Bt) {
  __shared__ float tile[128][17];
  const int kc = blockIdx.x;       // concept 0..63
  const int f0 = blockIdx.y * 128; // feature chunk
  const int t = threadIdx.x;
  {
    const int fl = t >> 1, dh = (t & 1) * 8;
    const float* g = Wp + ((size_t)kc * 2048 + f0 + fl) * 16 + dh;
    float4 v0 = *reinterpret_cast<const float4*>(g);
    float4 v1 = *reinterpret_cast<const float4*>(g + 4);
    tile[fl][dh + 0] = v0.x; tile[fl][dh + 1] = v0.y;
    tile[fl][dh + 2] = v0.z; tile[fl][dh + 3] = v0.w;
    tile[fl][dh + 4] = v1.x; tile[fl][dh + 5] = v1.y;
    tile[fl][dh + 6] = v1.z; tile[fl][dh + 7] = v1.w;
  }
  __syncthreads();
  {
    const int d = t >> 4, fi = (t & 15) * 8;
    float x[8];
#pragma unroll
    for (int u = 0; u < 8; ++u) x[u] = tile[fi + u][d];
    bf16x8 hv, lv;
#pragma unroll
    for (int u = 0; u < 8; ++u) {
      __bf16 h = (__bf16)x[u];
      hv[u] = h;
      lv[u] = (__bf16)(x[u] - (float)h);
    }
    const size_t row = (size_t)(kc * 16 + d) * 4096;
    *reinterpret_cast<bf16x8*>(Bt + row + f0 + fi) = hv;
    *reinterpret_cast<bf16x8*>(Bt + row + 2048 + f0 + fi) = lv;
  }
}

// ---------------- G: split-bf16 MFMA GEMM, theta = feat@Wp + bp ------------
// BM=128, BN=128, BK=32; 4 waves 2x2; wave tile 64x64 (4x4 frags); 3 MFMAs
// per frag pair (hh + lh + hl). XCD-ownership mapping: xcd = bid&7 owns
// m-tiles {4*xcd..4*xcd+3} x all 8 n-tiles (A-slab 4 MB L2-resident).
__global__ __launch_bounds__(256, 1) void gemm_theta(
    const bf16_t* __restrict__ Ahg, const bf16_t* __restrict__ Alg,
    const bf16_t* __restrict__ Bt, const float* __restrict__ bias,
    float* __restrict__ C) {
  __shared__ bf16_t lds[2][4][128 * 32];  // [buf][Ah,Al,Bh,Bl][128 rows x 32k]
  const int t = threadIdx.x;
  const int bid = blockIdx.x;
  // bid -> (xcd = bid&7, s = bid>>3); m-tile = xcd*4 + (s&3); n-tile = s>>2.
  // Bijective over 256 blocks; blocks sharing an XCD share 4 m-tiles.
  const int m0 = (((bid & 7) << 2) + ((bid >> 3) & 3)) * 128;
  const int n0 = (bid >> 5) * 128;
  const int wave = t >> 6, lane = t & 63, quad = lane >> 4, l16 = lane & 15;
  const int wm = (wave >> 1) * 64, wn = (wave & 1) * 64;
  floatx4 acc[4][4] = {};

  // staging: slot = q*256 + t -> (row, chunk') = (slot>>2, slot&3).
  // LDS dest linear (gload_lds rule); LDS slot (r, c') holds GLOBAL chunk
  // c = c' ^ ((r>>1)&3). Key identical for r and r+64.
  const int srow = t >> 2;
  const int skey = (srow >> 1) & 3;
  const int c8 = (((t & 3) ^ skey)) * 8;  // swizzled source chunk (elements)
  const bf16_t* gAh0 = Ahg + (size_t)(m0 + srow) * 2048 + c8;
  const bf16_t* gAh1 = Ahg + (size_t)(m0 + 64 + srow) * 2048 + c8;
  const bf16_t* gAl0 = Alg + (size_t)(m0 + srow) * 2048 + c8;
  const bf16_t* gAl1 = Alg + (size_t)(m0 + 64 + srow) * 2048 + c8;
  const bf16_t* gBh0 = Bt + (size_t)(n0 + srow) * 4096 + c8;
  const bf16_t* gBh1 = Bt + (size_t)(n0 + 64 + srow) * 4096 + c8;
  // lo halves of Bt rows live at +2048

  auto stage = [&](int bf, int kk) {
    const int ko = kk * 32;
    gload16(gAh0 + ko, &lds[bf][0][t * 8]);
    gload16(gAh1 + ko, &lds[bf][0][(256 + t) * 8]);
    gload16(gAl0 + ko, &lds[bf][1][t * 8]);
    gload16(gAl1 + ko, &lds[bf][1][(256 + t) * 8]);
    gload16(gBh0 + ko, &lds[bf][2][t * 8]);
    gload16(gBh1 + ko, &lds[bf][2][(256 + t) * 8]);
    gload16(gBh0 + 2048 + ko, &lds[bf][3][t * 8]);
    gload16(gBh1 + 2048 + ko, &lds[bf][3][(256 + t) * 8]);
  };

  stage(0, 0);
  __syncthreads();  // drains vmcnt(0): buffer 0 ready

  // frag-read chunk key: row R = (mult of 16) + l16 -> (R>>1)&3 = (l16>>1)&3
  const int fkey = (l16 >> 1) & 3;
  const int qa = (quad ^ fkey) * 8;  // swizzled chunk offset (elements)

  int buf = 0;
  for (int kk = 0; kk < 64; ++kk) {
    if (kk < 63) stage(buf ^ 1, kk + 1);  // prefetch under compute
    bf16x8 ah[4], al[4], bh[4], bl[4];
#pragma unroll
    for (int r = 0; r < 4; ++r) {
      const int off = (wm + r * 16 + l16) * 32 + qa;
      ah[r] = *reinterpret_cast<const bf16x8*>(&lds[buf][0][off]);
      al[r] = *reinterpret_cast<const bf16x8*>(&lds[buf][1][off]);
    }
#pragma unroll
    for (int c = 0; c < 4; ++c) {
      const int off = (wn + c * 16 + l16) * 32 + qa;
      bh[c] = *reinterpret_cast<const bf16x8*>(&lds[buf][2][off]);
      bl[c] = *reinterpret_cast<const bf16x8*>(&lds[buf][3][off]);
    }
#pragma unroll
    for (int r = 0; r < 4; ++r)
#pragma unroll
      for (int c = 0; c < 4; ++c) {
        acc[r][c] = __builtin_amdgcn_mfma_f32_16x16x32_bf16(ah[r], bh[c],
                                                            acc[r][c], 0, 0, 0);
        acc[r][c] = __builtin_amdgcn_mfma_f32_16x16x32_bf16(al[r], bh[c],
                                                            acc[r][c], 0, 0, 0);
        acc[r][c] = __builtin_amdgcn_mfma_f32_16x16x32_bf16(ah[r], bl[c],
                                                            acc[r][c], 0, 0, 0);
      }
    __syncthreads();  // vmcnt(0)+lgkmcnt(0)+barrier: next buffer ready
    buf ^= 1;
  }

  // epilogue: C/D layout col=lane&15 (N), row=quad*4+i (M)
#pragma unroll
  for (int r = 0; r < 4; ++r) {
    const int row0 = m0 + wm + r * 16 + quad * 4;
#pragma unroll
    for (int c = 0; c < 4; ++c) {
      const int col = n0 + wn + c * 16 + l16;
      const float bb = bias[col];
#pragma unroll
      for (int i = 0; i < 4; ++i)
        C[(size_t)(row0 + i) * 1024 + col] = acc[r][c][i] + bb;
    }
  }
}

// ---------------- D: fused boxes + probs + pairwise (circular) + final -----
__global__ __launch_bounds__(256, 2) void fused_pair(
    const float* __restrict__ Th, const float* __restrict__ Wprob,
    const float* __restrict__ bprob, const float* __restrict__ Wbox,
    const float* __restrict__ bbox, const float* __restrict__ Wrel,
    const float* __restrict__ brel, float* __restrict__ out) {
  __shared__ float sboxes[64][17];  // pad 17: row-scatter reads <=2-way (free)
  __shared__ float spinv[64];       // 1 / prod_d log2(1+exp2(K3*(Z-z)))
  __shared__ float spc[64];
  __shared__ float swrel[4096];
  __shared__ float swbox[1024];
  __shared__ float sprod[33 * 66];  // row o=0..32 (circular offset), col i;
                                    // pad 66: phase-B lookup <=2-way banks
  __shared__ float sred[4];

  const int b = blockIdx.x;
  const int t = threadIdx.x;
  const float* th = Th + (size_t)b * 1024;
  float* out_task = out;           // [4096]
  float* out_conc = out + 4096;    // [4096][64]
  float* out_cond = out + 266240;  // [4096][64][64]

  if (t < 64) {
    const int k = t;
    const float* thk = th + k * 16;
    float4 a0 = reinterpret_cast<const float4*>(thk)[0];
    float4 a1 = reinterpret_cast<const float4*>(thk)[1];
    float4 a2 = reinterpret_cast<const float4*>(thk)[2];
    float4 a3 = reinterpret_cast<const float4*>(thk)[3];
    float z[8] = {a0.x, a0.y, a0.z, a0.w, a1.x, a1.y, a1.z, a1.w};
    float w1[8] = {a2.x, a2.y, a2.z, a2.w, a3.x, a3.y, a3.z, a3.w};
    float dp = 1.0f;
    float logit = bprob[k];
#pragma unroll
    for (int d = 0; d < 8; ++d) {
      const float spv = LN2 * lg2(1.0f + ex2(w1[d] * LOG2E));  // softplus
      const float Zd = z[d] + spv;
      const float denl = lg2(1.0f + ex2((Zd - z[d]) * K3C));   // >= 1
      dp *= denl;
      logit += z[d] * Wprob[k * 16 + d] + Zd * Wprob[k * 16 + 8 + d];
      sboxes[k][d] = z[d];
      sboxes[k][8 + d] = Zd;
    }
    spinv[k] = 1.0f / dp;
    const float pk = 1.0f / (1.0f + ex2(-logit * LOG2E));
    spc[k] = pk;
    out_conc[(size_t)b * 64 + k] = pk;
  }
#pragma unroll
  for (int q = 0; q < 4; ++q)
    reinterpret_cast<float4*>(swrel)[q * 256 + t] =
        reinterpret_cast<const float4*>(Wrel)[q * 256 + t];
  reinterpret_cast<float4*>(swbox)[t] = reinterpret_cast<const float4*>(Wbox)[t];
  __syncthreads();

  const int wv = t >> 6, lane = t & 63;

  // ---- phase A: circular-offset numerators. Thread owns box i = lane in
  // registers; pair (i, (i+o)&63) for o = wv*8+oo (0..31) + o=32 for t<64.
  // Math symmetric in (i,j) -> identical values to triangular enumeration.
  float zi[8], Zi[8];
#pragma unroll
  for (int d = 0; d < 8; ++d) {
    zi[d] = sboxes[lane][d];
    Zi[d] = sboxes[lane][8 + d];
  }

#pragma unroll 2
  for (int oo = 0; oo < 8; ++oo) {
    const int o = wv * 8 + oo;
    const int j = (lane + o) & 63;
    float prodn = 1.0f;
#pragma unroll
    for (int d = 0; d < 8; ++d) {
      const float zjd = sboxes[j][d], Zjd = sboxes[j][8 + d];
      const float u = ex2(-fabsf(zi[d] - zjd) * K1C);
      const float uZ = ex2(-fabsf(Zi[d] - Zjd) * K1C);
      const float lsum = lg2(fmaf(u, uZ, 1.0f + u + uZ));
      const float gap = fminf(Zi[d], Zjd) - fmaxf(zi[d], zjd);
      const float E = ex2(fmaf(gap, K3C, -0.2f * lsum));
      prodn *= lg2(1.0f + E);
    }
    sprod[o * 66 + lane] = prodn;
  }
  if (t < 64) {  // o = 32 row (each unordered o=32 pair computed twice; same value)
    const int j = (lane + 32) & 63;
    float prodn = 1.0f;
#pragma unroll
    for (int d = 0; d < 8; ++d) {
      const float zjd = sboxes[j][d], Zjd = sboxes[j][8 + d];
      const float u = ex2(-fabsf(zi[d] - zjd) * K1C);
      const float uZ = ex2(-fabsf(Zi[d] - Zjd) * K1C);
      const float lsum = lg2(fmaf(u, uZ, 1.0f + u + uZ));
      const float gap = fminf(Zi[d], Zjd) - fmaxf(zi[d], zjd);
      const float E = ex2(fmaf(gap, K3C, -0.2f * lsum));
      prodn *= lg2(1.0f + E);
    }
    sprod[32 * 66 + lane] = prodn;
  }
  __syncthreads();

  // ---- phase B: expand to ordered pairs, coalesced stores ----
  const float pinvj = spinv[lane];
  float rsum = 0.0f;
#pragma unroll 4
  for (int ii = 0; ii < 16; ++ii) {
    const int i = wv * 16 + ii;
    const int od = (lane - i) & 63;
    const bool sel = od <= 32;
    const int so = sel ? od : 64 - od;
    const int si = sel ? i : lane;
    const float prodn = sprod[so * 66 + si];
    float cond = prodn * pinvj;
    cond = fminf(fmaxf(cond, 1e-6f), 1.0f - 1e-6f);
    out_cond[(size_t)b * 4096 + i * 64 + lane] = cond;
    rsum = fmaf(cond, swrel[i * 64 + lane], rsum);
  }

  float bsum = 0.0f;
#pragma unroll
  for (int q = 0; q < 4; ++q) {
    const int idx = t + 256 * q;
    const int k = idx >> 4, c = idx & 15;
    bsum = fmaf(sboxes[k][c] * spc[k], swbox[idx], bsum);
  }
  float total = rsum + bsum;
#pragma unroll
  for (int off = 32; off > 0; off >>= 1) total += __shfl_down(total, off, 64);
  if (lane == 0) sred[wv] = total;
  __syncthreads();
  if (t == 0) {
    const float s = sred[0] + sred[1] + sred[2] + sred[3] + bbox[0] + brel[0];
    out_task[b] = 1.0f / (1.0f + ex2(-s * LOG2E));
  }
}

// ---------------------------------------------------------------------------
extern "C" void kernel_launch(void* const* d_in, const int* in_sizes, int n_in,
                              void* d_out, int out_size, void* d_ws, size_t ws_size,
                              hipStream_t stream) {
  const float* feat = (const float*)d_in[0];
  const float* Wp = (const float*)d_in[1];
  const float* bp = (const float*)d_in[2];
  const float* Wprob = (const float*)d_in[3];
  const float* bprob = (const float*)d_in[4];
  const float* Wbox = (const float*)d_in[5];
  const float* bbox = (const float*)d_in[6];
  const float* Wrel = (const float*)d_in[7];
  const float* brel = (const float*)d_in[8];
  float* out = (float*)d_out;

  char* ws = (char*)d_ws;
  bf16_t* Bt = (bf16_t*)ws;                        //  8 MB: [1024][4096] bf16
  float* Th = (float*)(ws + (size_t)(8 << 20));    // 16 MB: [4096][1024] f32
  bf16_t* Ah = (bf16_t*)(ws + (size_t)(24 << 20)); // 16 MB: [4096][2048] bf16
  bf16_t* Al = (bf16_t*)(ws + (size_t)(40 << 20)); // 16 MB: [4096][2048] bf16

  prep_a<<<4096, 256, 0, stream>>>(feat, Ah, Al);
  prep_b<<<dim3(64, 16), 256, 0, stream>>>(Wp, Bt);
  gemm_theta<<<256, 256, 0, stream>>>(Ah, Al, Bt, bp, Th);
  fused_pair<<<4096, 256, 0, stream>>>(Th, Wprob, bprob, Wbox, bbox, Wrel, brel, out);
}

// Round 5
// 344.197 us; speedup vs baseline: 1.0591x; 1.0591x over previous
//
#include <hip/hip_runtime.h>
#include <cstdint>
#include <cstddef>

// ---------------------------------------------------------------------------
// BoxEmbeddingCBM: B=4096, F=2048, K=64, D=8, VOL_TEMP=0.5, INT_TEMP=0.1
//
// ROUND 12 (DIAGNOSTIC):
//   - fused_pair: reverted to the proven R10 triangular form (R11 circular
//     regressed 123->210 via ILP collapse). One safe change: the q=8 tail
//     (32 pairs) is now a wave-0-only block instead of 224 exec-masked
//     lanes issuing full pair math in all 4 waves. Identical pair set.
//   - gemm_theta: reverted to R10 grid/mapping (equivalent to R11's XCD map
//     under round-robin dispatch). Launched TWICE: second run overwrites Th
//     with bit-identical values (sequential dispatches, no race). Purpose:
//     gemm has never appeared in top-5; with fused at ~116us and gemm at
//     ~119us x2, its FETCH_SIZE / MfmaUtil / VALUBusy / Occupancy finally
//     surface and decide HBM-streaming vs LLC-BW-bound.
// Outputs f32. ws: Bt 8 MB + Th 16 MB + Ah 16 MB + Al 16 MB = 56 MB.
// ---------------------------------------------------------------------------

typedef __bf16 bf16_t;
typedef __bf16 bf16x4 __attribute__((ext_vector_type(4)));
typedef __bf16 bf16x8 __attribute__((ext_vector_type(8)));
typedef float floatx4 __attribute__((ext_vector_type(4)));

#define LOG2E 1.4426950408889634f
#define LN2 0.6931471805599453f
#define K1C 14.426950408889634f  /* LOG2E / INT_TEMP */
#define K3C 2.8853900817779268f  /* 2*LOG2E  (vol beta = 1/VOL_TEMP = 2) */

__device__ __forceinline__ float ex2(float x) { return __builtin_exp2f(x); }
__device__ __forceinline__ float lg2(float x) { return __builtin_log2f(x); }

__device__ __forceinline__ void gload16(const bf16_t* g, bf16_t* l) {
  __builtin_amdgcn_global_load_lds(
      (const __attribute__((address_space(1))) void*)g,
      (__attribute__((address_space(3))) void*)l, 16, 0, 0);
}

// ---------------- P1: split A [4096][2048] f32 -> Ah/Al bf16 ---------------
__global__ __launch_bounds__(256) void prep_a(const float* __restrict__ A,
                                              bf16_t* __restrict__ Ah,
                                              bf16_t* __restrict__ Al) {
  const size_t i = ((size_t)blockIdx.x * 256 + threadIdx.x) * 8;
  const float4 v0 = *reinterpret_cast<const float4*>(A + i);
  const float4 v1 = *reinterpret_cast<const float4*>(A + i + 4);
  const float x[8] = {v0.x, v0.y, v0.z, v0.w, v1.x, v1.y, v1.z, v1.w};
  bf16x8 h, l;
#pragma unroll
  for (int u = 0; u < 8; ++u) {
    const __bf16 hv = (__bf16)x[u];
    h[u] = hv;
    l[u] = (__bf16)(x[u] - (float)hv);
  }
  *reinterpret_cast<bf16x8*>(Ah + i) = h;
  *reinterpret_cast<bf16x8*>(Al + i) = l;
}

// ---------------- P2: transpose+split Wp into Bt [1024][4096] --------------
// row n = kc*16+d; cols 0..2047 = hi(bf16), 2048..4095 = lo(bf16)
__global__ __launch_bounds__(256, 2) void prep_b(const float* __restrict__ Wp,
                                                 bf16_t* __restrict__ Bt) {
  __shared__ float tile[128][17];
  const int kc = blockIdx.x;       // concept 0..63
  const int f0 = blockIdx.y * 128; // feature chunk
  const int t = threadIdx.x;
  {
    const int fl = t >> 1, dh = (t & 1) * 8;
    const float* g = Wp + ((size_t)kc * 2048 + f0 + fl) * 16 + dh;
    float4 v0 = *reinterpret_cast<const float4*>(g);
    float4 v1 = *reinterpret_cast<const float4*>(g + 4);
    tile[fl][dh + 0] = v0.x; tile[fl][dh + 1] = v0.y;
    tile[fl][dh + 2] = v0.z; tile[fl][dh + 3] = v0.w;
    tile[fl][dh + 4] = v1.x; tile[fl][dh + 5] = v1.y;
    tile[fl][dh + 6] = v1.z; tile[fl][dh + 7] = v1.w;
  }
  __syncthreads();
  {
    const int d = t >> 4, fi = (t & 15) * 8;
    float x[8];
#pragma unroll
    for (int u = 0; u < 8; ++u) x[u] = tile[fi + u][d];
    bf16x8 hv, lv;
#pragma unroll
    for (int u = 0; u < 8; ++u) {
      __bf16 h = (__bf16)x[u];
      hv[u] = h;
      lv[u] = (__bf16)(x[u] - (float)h);
    }
    const size_t row = (size_t)(kc * 16 + d) * 4096;
    *reinterpret_cast<bf16x8*>(Bt + row + f0 + fi) = hv;
    *reinterpret_cast<bf16x8*>(Bt + row + 2048 + f0 + fi) = lv;
  }
}

// ---------------- G: split-bf16 MFMA GEMM, theta = feat@Wp + bp ------------
// BM=128, BN=128, BK=32; 4 waves 2x2; wave tile 64x64 (4x4 frags); 3 MFMAs
// per frag pair (hh + lh + hl). Pre-split inputs; global_load_lds staging
// into XOR-chunk-swizzled linear LDS; 2-phase double buffer.
__global__ __launch_bounds__(256, 1) void gemm_theta(
    const bf16_t* __restrict__ Ahg, const bf16_t* __restrict__ Alg,
    const bf16_t* __restrict__ Bt, const float* __restrict__ bias,
    float* __restrict__ C) {
  __shared__ bf16_t lds[2][4][128 * 32];  // [buf][Ah,Al,Bh,Bl][128 rows x 32k]
  const int t = threadIdx.x;
  const int m0 = blockIdx.x * 128, n0 = blockIdx.y * 128;
  const int wave = t >> 6, lane = t & 63, quad = lane >> 4, l16 = lane & 15;
  const int wm = (wave >> 1) * 64, wn = (wave & 1) * 64;
  floatx4 acc[4][4] = {};

  // staging: slot = q*256 + t -> (row, chunk') = (slot>>2, slot&3).
  // LDS dest linear (gload_lds rule); LDS slot (r, c') holds GLOBAL chunk
  // c = c' ^ ((r>>1)&3). Key identical for r and r+64.
  const int srow = t >> 2;
  const int skey = (srow >> 1) & 3;
  const int c8 = (((t & 3) ^ skey)) * 8;  // swizzled source chunk (elements)
  const bf16_t* gAh0 = Ahg + (size_t)(m0 + srow) * 2048 + c8;
  const bf16_t* gAh1 = Ahg + (size_t)(m0 + 64 + srow) * 2048 + c8;
  const bf16_t* gAl0 = Alg + (size_t)(m0 + srow) * 2048 + c8;
  const bf16_t* gAl1 = Alg + (size_t)(m0 + 64 + srow) * 2048 + c8;
  const bf16_t* gBh0 = Bt + (size_t)(n0 + srow) * 4096 + c8;
  const bf16_t* gBh1 = Bt + (size_t)(n0 + 64 + srow) * 4096 + c8;
  // lo halves of Bt rows live at +2048

  auto stage = [&](int bf, int kk) {
    const int ko = kk * 32;
    gload16(gAh0 + ko, &lds[bf][0][t * 8]);
    gload16(gAh1 + ko, &lds[bf][0][(256 + t) * 8]);
    gload16(gAl0 + ko, &lds[bf][1][t * 8]);
    gload16(gAl1 + ko, &lds[bf][1][(256 + t) * 8]);
    gload16(gBh0 + ko, &lds[bf][2][t * 8]);
    gload16(gBh1 + ko, &lds[bf][2][(256 + t) * 8]);
    gload16(gBh0 + 2048 + ko, &lds[bf][3][t * 8]);
    gload16(gBh1 + 2048 + ko, &lds[bf][3][(256 + t) * 8]);
  };

  stage(0, 0);
  __syncthreads();  // drains vmcnt(0): buffer 0 ready

  // frag-read chunk key: row R = (mult of 16) + l16 -> (R>>1)&3 = (l16>>1)&3
  const int fkey = (l16 >> 1) & 3;
  const int qa = (quad ^ fkey) * 8;  // swizzled chunk offset (elements)

  int buf = 0;
  for (int kk = 0; kk < 64; ++kk) {
    if (kk < 63) stage(buf ^ 1, kk + 1);  // prefetch under compute
    bf16x8 ah[4], al[4], bh[4], bl[4];
#pragma unroll
    for (int r = 0; r < 4; ++r) {
      const int off = (wm + r * 16 + l16) * 32 + qa;
      ah[r] = *reinterpret_cast<const bf16x8*>(&lds[buf][0][off]);
      al[r] = *reinterpret_cast<const bf16x8*>(&lds[buf][1][off]);
    }
#pragma unroll
    for (int c = 0; c < 4; ++c) {
      const int off = (wn + c * 16 + l16) * 32 + qa;
      bh[c] = *reinterpret_cast<const bf16x8*>(&lds[buf][2][off]);
      bl[c] = *reinterpret_cast<const bf16x8*>(&lds[buf][3][off]);
    }
#pragma unroll
    for (int r = 0; r < 4; ++r)
#pragma unroll
      for (int c = 0; c < 4; ++c) {
        acc[r][c] = __builtin_amdgcn_mfma_f32_16x16x32_bf16(ah[r], bh[c],
                                                            acc[r][c], 0, 0, 0);
        acc[r][c] = __builtin_amdgcn_mfma_f32_16x16x32_bf16(al[r], bh[c],
                                                            acc[r][c], 0, 0, 0);
        acc[r][c] = __builtin_amdgcn_mfma_f32_16x16x32_bf16(ah[r], bl[c],
                                                            acc[r][c], 0, 0, 0);
      }
    __syncthreads();  // vmcnt(0)+lgkmcnt(0)+barrier: next buffer ready
    buf ^= 1;
  }

  // epilogue: C/D layout col=lane&15 (N), row=quad*4+i (M)
#pragma unroll
  for (int r = 0; r < 4; ++r) {
    const int row0 = m0 + wm + r * 16 + quad * 4;
#pragma unroll
    for (int c = 0; c < 4; ++c) {
      const int col = n0 + wn + c * 16 + l16;
      const float bb = bias[col];
#pragma unroll
      for (int i = 0; i < 4; ++i)
        C[(size_t)(row0 + i) * 1024 + col] = acc[r][c][i] + bb;
    }
  }
}

// ---------------- D: fused boxes + probs + pairwise (symmetric) + final ----
__global__ __launch_bounds__(256, 2) void fused_pair(
    const float* __restrict__ Th, const float* __restrict__ Wprob,
    const float* __restrict__ bprob, const float* __restrict__ Wbox,
    const float* __restrict__ bbox, const float* __restrict__ Wrel,
    const float* __restrict__ brel, float* __restrict__ out) {
  __shared__ float sboxes[64][17];  // pad 17: scattered row reads conflict-free
  __shared__ float spinv[64];       // 1 / prod_d log2(1+exp2(K3*(Z-z)))
  __shared__ float spc[64];
  __shared__ float swrel[4096];
  __shared__ float swbox[1024];
  __shared__ float sprod[2080];     // upper-triangle numerators (i<=j)
  __shared__ float sred[4];

  const int b = blockIdx.x;
  const int t = threadIdx.x;
  const float* th = Th + (size_t)b * 1024;
  float* out_task = out;           // [4096]
  float* out_conc = out + 4096;    // [4096][64]
  float* out_cond = out + 266240;  // [4096][64][64]

  if (t < 64) {
    const int k = t;
    const float* thk = th + k * 16;
    float4 a0 = reinterpret_cast<const float4*>(thk)[0];
    float4 a1 = reinterpret_cast<const float4*>(thk)[1];
    float4 a2 = reinterpret_cast<const float4*>(thk)[2];
    float4 a3 = reinterpret_cast<const float4*>(thk)[3];
    float z[8] = {a0.x, a0.y, a0.z, a0.w, a1.x, a1.y, a1.z, a1.w};
    float w1[8] = {a2.x, a2.y, a2.z, a2.w, a3.x, a3.y, a3.z, a3.w};
    float dp = 1.0f;
    float logit = bprob[k];
#pragma unroll
    for (int d = 0; d < 8; ++d) {
      const float spv = LN2 * lg2(1.0f + ex2(w1[d] * LOG2E));  // softplus
      const float Zd = z[d] + spv;
      const float denl = lg2(1.0f + ex2((Zd - z[d]) * K3C));   // >= 1
      dp *= denl;
      logit += z[d] * Wprob[k * 16 + d] + Zd * Wprob[k * 16 + 8 + d];
      sboxes[k][d] = z[d];
      sboxes[k][8 + d] = Zd;
    }
    spinv[k] = 1.0f / dp;
    const float pk = 1.0f / (1.0f + ex2(-logit * LOG2E));
    spc[k] = pk;
    out_conc[(size_t)b * 64 + k] = pk;
  }
#pragma unroll
  for (int q = 0; q < 4; ++q)
    reinterpret_cast<float4*>(swrel)[q * 256 + t] =
        reinterpret_cast<const float4*>(Wrel)[q * 256 + t];
  reinterpret_cast<float4*>(swbox)[t] = reinterpret_cast<const float4*>(Wbox)[t];
  __syncthreads();

  // ---- phase A: unique numerators over the 2080 (i<=j) pairs ----
  auto pairnum = [&](int p) {
    int j = (int)((sqrtf((float)(8 * p + 1)) - 1.0f) * 0.5f);
    if ((j + 1) * (j + 2) / 2 <= p) ++j;
    if (j * (j + 1) / 2 > p) --j;
    const int i = p - j * (j + 1) / 2;  // i <= j
    float prodn = 1.0f;
#pragma unroll
    for (int d = 0; d < 8; ++d) {
      const float zi = sboxes[i][d], Zi = sboxes[i][8 + d];
      const float zjd = sboxes[j][d], Zjd = sboxes[j][8 + d];
      const float u = ex2(-fabsf(zi - zjd) * K1C);
      const float uZ = ex2(-fabsf(Zi - Zjd) * K1C);
      const float lsum = lg2(fmaf(u, uZ, 1.0f + u + uZ));
      const float gap = fminf(Zi, Zjd) - fmaxf(zi, zjd);
      const float E = ex2(fmaf(gap, K3C, -0.2f * lsum));
      prodn *= lg2(1.0f + E);
    }
    sprod[p] = prodn;
  };
#pragma unroll
  for (int q = 0; q < 8; ++q) pairnum(t + 256 * q);  // p <= 2047 < 2080
  if (t < 32) pairnum(2048 + t);  // tail: wave-0 only; waves 1-3 branch over
  __syncthreads();

  // ---- phase B: expand to ordered pairs, coalesced stores ----
  const int wv = t >> 6, lane = t & 63;
  const float pinvj = spinv[lane];
  float rsum = 0.0f;
#pragma unroll 4
  for (int ii = 0; ii < 16; ++ii) {
    const int i = wv * 16 + ii;
    const int lo = min(i, lane), hi = max(i, lane);
    const float prodn = sprod[hi * (hi + 1) / 2 + lo];
    float cond = prodn * pinvj;
    cond = fminf(fmaxf(cond, 1e-6f), 1.0f - 1e-6f);
    out_cond[(size_t)b * 4096 + i * 64 + lane] = cond;
    rsum = fmaf(cond, swrel[i * 64 + lane], rsum);
  }

  float bsum = 0.0f;
#pragma unroll
  for (int q = 0; q < 4; ++q) {
    const int idx = t + 256 * q;
    const int k = idx >> 4, c = idx & 15;
    bsum = fmaf(sboxes[k][c] * spc[k], swbox[idx], bsum);
  }
  float total = rsum + bsum;
#pragma unroll
  for (int off = 32; off > 0; off >>= 1) total += __shfl_down(total, off, 64);
  if (lane == 0) sred[wv] = total;
  __syncthreads();
  if (t == 0) {
    const float s = sred[0] + sred[1] + sred[2] + sred[3] + bbox[0] + brel[0];
    out_task[b] = 1.0f / (1.0f + ex2(-s * LOG2E));
  }
}

// ---------------------------------------------------------------------------
extern "C" void kernel_launch(void* const* d_in, const int* in_sizes, int n_in,
                              void* d_out, int out_size, void* d_ws, size_t ws_size,
                              hipStream_t stream) {
  const float* feat = (const float*)d_in[0];
  const float* Wp = (const float*)d_in[1];
  const float* bp = (const float*)d_in[2];
  const float* Wprob = (const float*)d_in[3];
  const float* bprob = (const float*)d_in[4];
  const float* Wbox = (const float*)d_in[5];
  const float* bbox = (const float*)d_in[6];
  const float* Wrel = (const float*)d_in[7];
  const float* brel = (const float*)d_in[8];
  float* out = (float*)d_out;

  char* ws = (char*)d_ws;
  bf16_t* Bt = (bf16_t*)ws;                        //  8 MB: [1024][4096] bf16
  float* Th = (float*)(ws + (size_t)(8 << 20));    // 16 MB: [4096][1024] f32
  bf16_t* Ah = (bf16_t*)(ws + (size_t)(24 << 20)); // 16 MB: [4096][2048] bf16
  bf16_t* Al = (bf16_t*)(ws + (size_t)(40 << 20)); // 16 MB: [4096][2048] bf16

  prep_a<<<4096, 256, 0, stream>>>(feat, Ah, Al);
  prep_b<<<dim3(64, 16), 256, 0, stream>>>(Wp, Bt);
  // DIAGNOSTIC: gemm launched twice (bit-identical Th both times) so its
  // counters surface in the top-5 table. Remove next round.
  gemm_theta<<<dim3(32, 8), 256, 0, stream>>>(Ah, Al, Bt, bp, Th);
  gemm_theta<<<dim3(32, 8), 256, 0, stream>>>(Ah, Al, Bt, bp, Th);
  fused_pair<<<4096, 256, 0, stream>>>(Th, Wprob, bprob, Wbox, bbox, Wrel, brel, out);
}

// Round 6
// 276.878 us; speedup vs baseline: 1.3166x; 1.2431x over previous
//
#include <hip/hip_runtime.h>
#include <cstdint>
#include <cstddef>

// ---------------------------------------------------------------------------
// BoxEmbeddingCBM: B=4096, F=2048, K=64, D=8, VOL_TEMP=0.5, INT_TEMP=0.1
//
// ROUND 13:
//   Budget (R12 double-launch subtraction): fused 123.5 | gemm 26.5 |
//   preps ~14 | fixed overhead ~118. gemm was NEVER the problem.
//   - fused_pair: phase A restored VERBATIM to the proven R10 form (R12's
//     lambda/tail restructure cost +36us via schedule collapse). Only
//     change: launch_bounds (256,2)->(256,4) — occupancy probe, codegen
//     should be untouched (VGPR 52 << 128, LDS 33.8KB*4 fits).
//   - prep_ab: prep_a and prep_b merged into one block-partitioned kernel
//     (5120 blocks). Probes whether the ~118us overhead is per-launch.
//   - gemm_theta: R10 form, single launch.
// Outputs f32. ws: Bt 8 MB + Th 16 MB + Ah 16 MB + Al 16 MB = 56 MB.
// ---------------------------------------------------------------------------

typedef __bf16 bf16_t;
typedef __bf16 bf16x4 __attribute__((ext_vector_type(4)));
typedef __bf16 bf16x8 __attribute__((ext_vector_type(8)));
typedef float floatx4 __attribute__((ext_vector_type(4)));

#define LOG2E 1.4426950408889634f
#define LN2 0.6931471805599453f
#define K1C 14.426950408889634f  /* LOG2E / INT_TEMP */
#define K3C 2.8853900817779268f  /* 2*LOG2E  (vol beta = 1/VOL_TEMP = 2) */

__device__ __forceinline__ float ex2(float x) { return __builtin_exp2f(x); }
__device__ __forceinline__ float lg2(float x) { return __builtin_log2f(x); }

__device__ __forceinline__ void gload16(const bf16_t* g, bf16_t* l) {
  __builtin_amdgcn_global_load_lds(
      (const __attribute__((address_space(1))) void*)g,
      (__attribute__((address_space(3))) void*)l, 16, 0, 0);
}

// ---------------- P: merged prep (blocks 0..4095 = A-split; 4096..5119 = Wp
// transpose+split). Block-granular branch; no intra-wave divergence. --------
__global__ __launch_bounds__(256, 2) void prep_ab(
    const float* __restrict__ A, bf16_t* __restrict__ Ah,
    bf16_t* __restrict__ Al, const float* __restrict__ Wp,
    bf16_t* __restrict__ Bt) {
  __shared__ float tile[128][17];
  const int bid = blockIdx.x;
  const int t = threadIdx.x;
  if (bid < 4096) {
    // ---- prep_a body: split A [4096][2048] f32 -> Ah/Al bf16 ----
    const size_t i = ((size_t)bid * 256 + t) * 8;
    const float4 v0 = *reinterpret_cast<const float4*>(A + i);
    const float4 v1 = *reinterpret_cast<const float4*>(A + i + 4);
    const float x[8] = {v0.x, v0.y, v0.z, v0.w, v1.x, v1.y, v1.z, v1.w};
    bf16x8 h, l;
#pragma unroll
    for (int u = 0; u < 8; ++u) {
      const __bf16 hv = (__bf16)x[u];
      h[u] = hv;
      l[u] = (__bf16)(x[u] - (float)hv);
    }
    *reinterpret_cast<bf16x8*>(Ah + i) = h;
    *reinterpret_cast<bf16x8*>(Al + i) = l;
    return;
  }
  // ---- prep_b body: transpose+split Wp into Bt [1024][4096] ----
  // row n = kc*16+d; cols 0..2047 = hi(bf16), 2048..4095 = lo(bf16)
  const int pb = bid - 4096;
  const int kc = pb >> 4;          // concept 0..63
  const int f0 = (pb & 15) * 128;  // feature chunk
  {
    const int fl = t >> 1, dh = (t & 1) * 8;
    const float* g = Wp + ((size_t)kc * 2048 + f0 + fl) * 16 + dh;
    float4 v0 = *reinterpret_cast<const float4*>(g);
    float4 v1 = *reinterpret_cast<const float4*>(g + 4);
    tile[fl][dh + 0] = v0.x; tile[fl][dh + 1] = v0.y;
    tile[fl][dh + 2] = v0.z; tile[fl][dh + 3] = v0.w;
    tile[fl][dh + 4] = v1.x; tile[fl][dh + 5] = v1.y;
    tile[fl][dh + 6] = v1.z; tile[fl][dh + 7] = v1.w;
  }
  __syncthreads();
  {
    const int d = t >> 4, fi = (t & 15) * 8;
    float x[8];
#pragma unroll
    for (int u = 0; u < 8; ++u) x[u] = tile[fi + u][d];
    bf16x8 hv, lv;
#pragma unroll
    for (int u = 0; u < 8; ++u) {
      __bf16 h = (__bf16)x[u];
      hv[u] = h;
      lv[u] = (__bf16)(x[u] - (float)h);
    }
    const size_t row = (size_t)(kc * 16 + d) * 4096;
    *reinterpret_cast<bf16x8*>(Bt + row + f0 + fi) = hv;
    *reinterpret_cast<bf16x8*>(Bt + row + 2048 + f0 + fi) = lv;
  }
}

// ---------------- G: split-bf16 MFMA GEMM, theta = feat@Wp + bp ------------
// BM=128, BN=128, BK=32; 4 waves 2x2; wave tile 64x64 (4x4 frags); 3 MFMAs
// per frag pair (hh + lh + hl). Pre-split inputs; global_load_lds staging
// into XOR-chunk-swizzled linear LDS; 2-phase double buffer.
__global__ __launch_bounds__(256, 1) void gemm_theta(
    const bf16_t* __restrict__ Ahg, const bf16_t* __restrict__ Alg,
    const bf16_t* __restrict__ Bt, const float* __restrict__ bias,
    float* __restrict__ C) {
  __shared__ bf16_t lds[2][4][128 * 32];  // [buf][Ah,Al,Bh,Bl][128 rows x 32k]
  const int t = threadIdx.x;
  const int m0 = blockIdx.x * 128, n0 = blockIdx.y * 128;
  const int wave = t >> 6, lane = t & 63, quad = lane >> 4, l16 = lane & 15;
  const int wm = (wave >> 1) * 64, wn = (wave & 1) * 64;
  floatx4 acc[4][4] = {};

  // staging: slot = q*256 + t -> (row, chunk') = (slot>>2, slot&3).
  // LDS dest linear (gload_lds rule); LDS slot (r, c') holds GLOBAL chunk
  // c = c' ^ ((r>>1)&3). Key identical for r and r+64.
  const int srow = t >> 2;
  const int skey = (srow >> 1) & 3;
  const int c8 = (((t & 3) ^ skey)) * 8;  // swizzled source chunk (elements)
  const bf16_t* gAh0 = Ahg + (size_t)(m0 + srow) * 2048 + c8;
  const bf16_t* gAh1 = Ahg + (size_t)(m0 + 64 + srow) * 2048 + c8;
  const bf16_t* gAl0 = Alg + (size_t)(m0 + srow) * 2048 + c8;
  const bf16_t* gAl1 = Alg + (size_t)(m0 + 64 + srow) * 2048 + c8;
  const bf16_t* gBh0 = Bt + (size_t)(n0 + srow) * 4096 + c8;
  const bf16_t* gBh1 = Bt + (size_t)(n0 + 64 + srow) * 4096 + c8;
  // lo halves of Bt rows live at +2048

  auto stage = [&](int bf, int kk) {
    const int ko = kk * 32;
    gload16(gAh0 + ko, &lds[bf][0][t * 8]);
    gload16(gAh1 + ko, &lds[bf][0][(256 + t) * 8]);
    gload16(gAl0 + ko, &lds[bf][1][t * 8]);
    gload16(gAl1 + ko, &lds[bf][1][(256 + t) * 8]);
    gload16(gBh0 + ko, &lds[bf][2][t * 8]);
    gload16(gBh1 + ko, &lds[bf][2][(256 + t) * 8]);
    gload16(gBh0 + 2048 + ko, &lds[bf][3][t * 8]);
    gload16(gBh1 + 2048 + ko, &lds[bf][3][(256 + t) * 8]);
  };

  stage(0, 0);
  __syncthreads();  // drains vmcnt(0): buffer 0 ready

  // frag-read chunk key: row R = (mult of 16) + l16 -> (R>>1)&3 = (l16>>1)&3
  const int fkey = (l16 >> 1) & 3;
  const int qa = (quad ^ fkey) * 8;  // swizzled chunk offset (elements)

  int buf = 0;
  for (int kk = 0; kk < 64; ++kk) {
    if (kk < 63) stage(buf ^ 1, kk + 1);  // prefetch under compute
    bf16x8 ah[4], al[4], bh[4], bl[4];
#pragma unroll
    for (int r = 0; r < 4; ++r) {
      const int off = (wm + r * 16 + l16) * 32 + qa;
      ah[r] = *reinterpret_cast<const bf16x8*>(&lds[buf][0][off]);
      al[r] = *reinterpret_cast<const bf16x8*>(&lds[buf][1][off]);
    }
#pragma unroll
    for (int c = 0; c < 4; ++c) {
      const int off = (wn + c * 16 + l16) * 32 + qa;
      bh[c] = *reinterpret_cast<const bf16x8*>(&lds[buf][2][off]);
      bl[c] = *reinterpret_cast<const bf16x8*>(&lds[buf][3][off]);
    }
#pragma unroll
    for (int r = 0; r < 4; ++r)
#pragma unroll
      for (int c = 0; c < 4; ++c) {
        acc[r][c] = __builtin_amdgcn_mfma_f32_16x16x32_bf16(ah[r], bh[c],
                                                            acc[r][c], 0, 0, 0);
        acc[r][c] = __builtin_amdgcn_mfma_f32_16x16x32_bf16(al[r], bh[c],
                                                            acc[r][c], 0, 0, 0);
        acc[r][c] = __builtin_amdgcn_mfma_f32_16x16x32_bf16(ah[r], bl[c],
                                                            acc[r][c], 0, 0, 0);
      }
    __syncthreads();  // vmcnt(0)+lgkmcnt(0)+barrier: next buffer ready
    buf ^= 1;
  }

  // epilogue: C/D layout col=lane&15 (N), row=quad*4+i (M)
#pragma unroll
  for (int r = 0; r < 4; ++r) {
    const int row0 = m0 + wm + r * 16 + quad * 4;
#pragma unroll
    for (int c = 0; c < 4; ++c) {
      const int col = n0 + wn + c * 16 + l16;
      const float bb = bias[col];
#pragma unroll
      for (int i = 0; i < 4; ++i)
        C[(size_t)(row0 + i) * 1024 + col] = acc[r][c][i] + bb;
    }
  }
}

// ---------------- D: fused boxes + probs + pairwise (symmetric) + final ----
// Phase A is the R10 form VERBATIM (proven 123.5us schedule; R11/R12
// restructures both regressed). Only launch_bounds min-blocks 2->4.
__global__ __launch_bounds__(256, 4) void fused_pair(
    const float* __restrict__ Th, const float* __restrict__ Wprob,
    const float* __restrict__ bprob, const float* __restrict__ Wbox,
    const float* __restrict__ bbox, const float* __restrict__ Wrel,
    const float* __restrict__ brel, float* __restrict__ out) {
  __shared__ float sboxes[64][17];  // pad 17: scattered row reads conflict-free
  __shared__ float spinv[64];       // 1 / prod_d log2(1+exp2(K3*(Z-z)))
  __shared__ float spc[64];
  __shared__ float swrel[4096];
  __shared__ float swbox[1024];
  __shared__ float sprod[2080];     // upper-triangle numerators (i<=j)
  __shared__ float sred[4];

  const int b = blockIdx.x;
  const int t = threadIdx.x;
  const float* th = Th + (size_t)b * 1024;
  float* out_task = out;           // [4096]
  float* out_conc = out + 4096;    // [4096][64]
  float* out_cond = out + 266240;  // [4096][64][64]

  if (t < 64) {
    const int k = t;
    const float* thk = th + k * 16;
    float4 a0 = reinterpret_cast<const float4*>(thk)[0];
    float4 a1 = reinterpret_cast<const float4*>(thk)[1];
    float4 a2 = reinterpret_cast<const float4*>(thk)[2];
    float4 a3 = reinterpret_cast<const float4*>(thk)[3];
    float z[8] = {a0.x, a0.y, a0.z, a0.w, a1.x, a1.y, a1.z, a1.w};
    float w1[8] = {a2.x, a2.y, a2.z, a2.w, a3.x, a3.y, a3.z, a3.w};
    float dp = 1.0f;
    float logit = bprob[k];
#pragma unroll
    for (int d = 0; d < 8; ++d) {
      const float spv = LN2 * lg2(1.0f + ex2(w1[d] * LOG2E));  // softplus
      const float Zd = z[d] + spv;
      const float denl = lg2(1.0f + ex2((Zd - z[d]) * K3C));   // >= 1
      dp *= denl;
      logit += z[d] * Wprob[k * 16 + d] + Zd * Wprob[k * 16 + 8 + d];
      sboxes[k][d] = z[d];
      sboxes[k][8 + d] = Zd;
    }
    spinv[k] = 1.0f / dp;
    const float pk = 1.0f / (1.0f + ex2(-logit * LOG2E));
    spc[k] = pk;
    out_conc[(size_t)b * 64 + k] = pk;
  }
#pragma unroll
  for (int q = 0; q < 4; ++q)
    reinterpret_cast<float4*>(swrel)[q * 256 + t] =
        reinterpret_cast<const float4*>(Wrel)[q * 256 + t];
  reinterpret_cast<float4*>(swbox)[t] = reinterpret_cast<const float4*>(Wbox)[t];
  __syncthreads();

  // ---- phase A: unique numerators over the 2080 (i<=j) pairs ----
#pragma unroll
  for (int q = 0; q < 9; ++q) {
    const int p = t + 256 * q;
    if (p < 2080) {
      int j = (int)((sqrtf((float)(8 * p + 1)) - 1.0f) * 0.5f);
      if ((j + 1) * (j + 2) / 2 <= p) ++j;
      if (j * (j + 1) / 2 > p) --j;
      const int i = p - j * (j + 1) / 2;  // i <= j
      float prodn = 1.0f;
#pragma unroll
      for (int d = 0; d < 8; ++d) {
        const float zi = sboxes[i][d], Zi = sboxes[i][8 + d];
        const float zjd = sboxes[j][d], Zjd = sboxes[j][8 + d];
        const float u = ex2(-fabsf(zi - zjd) * K1C);
        const float uZ = ex2(-fabsf(Zi - Zjd) * K1C);
        const float lsum = lg2(fmaf(u, uZ, 1.0f + u + uZ));
        const float gap = fminf(Zi, Zjd) - fmaxf(zi, zjd);
        const float E = ex2(fmaf(gap, K3C, -0.2f * lsum));
        prodn *= lg2(1.0f + E);
      }
      sprod[p] = prodn;
    }
  }
  __syncthreads();

  // ---- phase B: expand to ordered pairs, coalesced stores ----
  const int wv = t >> 6, lane = t & 63;
  const float pinvj = spinv[lane];
  float rsum = 0.0f;
#pragma unroll 4
  for (int ii = 0; ii < 16; ++ii) {
    const int i = wv * 16 + ii;
    const int lo = min(i, lane), hi = max(i, lane);
    const float prodn = sprod[hi * (hi + 1) / 2 + lo];
    float cond = prodn * pinvj;
    cond = fminf(fmaxf(cond, 1e-6f), 1.0f - 1e-6f);
    out_cond[(size_t)b * 4096 + i * 64 + lane] = cond;
    rsum = fmaf(cond, swrel[i * 64 + lane], rsum);
  }

  float bsum = 0.0f;
#pragma unroll
  for (int q = 0; q < 4; ++q) {
    const int idx = t + 256 * q;
    const int k = idx >> 4, c = idx & 15;
    bsum = fmaf(sboxes[k][c] * spc[k], swbox[idx], bsum);
  }
  float total = rsum + bsum;
#pragma unroll
  for (int off = 32; off > 0; off >>= 1) total += __shfl_down(total, off, 64);
  if (lane == 0) sred[wv] = total;
  __syncthreads();
  if (t == 0) {
    const float s = sred[0] + sred[1] + sred[2] + sred[3] + bbox[0] + brel[0];
    out_task[b] = 1.0f / (1.0f + ex2(-s * LOG2E));
  }
}

// ---------------------------------------------------------------------------
extern "C" void kernel_launch(void* const* d_in, const int* in_sizes, int n_in,
                              void* d_out, int out_size, void* d_ws, size_t ws_size,
                              hipStream_t stream) {
  const float* feat = (const float*)d_in[0];
  const float* Wp = (const float*)d_in[1];
  const float* bp = (const float*)d_in[2];
  const float* Wprob = (const float*)d_in[3];
  const float* bprob = (const float*)d_in[4];
  const float* Wbox = (const float*)d_in[5];
  const float* bbox = (const float*)d_in[6];
  const float* Wrel = (const float*)d_in[7];
  const float* brel = (const float*)d_in[8];
  float* out = (float*)d_out;

  char* ws = (char*)d_ws;
  bf16_t* Bt = (bf16_t*)ws;                        //  8 MB: [1024][4096] bf16
  float* Th = (float*)(ws + (size_t)(8 << 20));    // 16 MB: [4096][1024] f32
  bf16_t* Ah = (bf16_t*)(ws + (size_t)(24 << 20)); // 16 MB: [4096][2048] bf16
  bf16_t* Al = (bf16_t*)(ws + (size_t)(40 << 20)); // 16 MB: [4096][2048] bf16

  prep_ab<<<5120, 256, 0, stream>>>(feat, Ah, Al, Wp, Bt);
  gemm_theta<<<dim3(32, 8), 256, 0, stream>>>(Ah, Al, Bt, bp, Th);
  fused_pair<<<4096, 256, 0, stream>>>(Th, Wprob, bprob, Wbox, bbox, Wrel, brel, out);
}